// Round 1
// 544.727 us; speedup vs baseline: 1.1246x; 1.1246x over previous
//
#include <hip/hip_runtime.h>
#include <stdint.h>

#define HN 16
#define DHD 64
#define NSEQ 1024
#define JCOL 1026
#define JP 1056   // PV k-pad (mult of 32)
#define JP2 1088  // dots n-pad (mult of 64)
#define ROTD 32
#define MASKV -3.402823466e+38f

typedef unsigned short ushort_t;
typedef __attribute__((ext_vector_type(8))) short short8;
typedef __attribute__((ext_vector_type(4))) short short4v;
typedef __attribute__((ext_vector_type(4))) float f32x4;
typedef __attribute__((ext_vector_type(2))) float f32x2;

__device__ inline ushort_t f2b(float f){ union{float f; unsigned int i;} v; v.f=f; unsigned x=v.i;
  return (ushort_t)((x + 0x7FFFu + ((x>>16)&1u))>>16); }

__device__ inline void gld16(const void* g, void* l){
  __builtin_amdgcn_global_load_lds((const __attribute__((address_space(1))) void*)g,
                                   (__attribute__((address_space(3))) void*)l, 16, 0, 0);
}

// order-preserving sortable key <-> float (invertible)
__device__ inline unsigned key_of(float f){
  unsigned u = __float_as_uint(f);
  return (u & 0x80000000u) ? ~u : (u | 0x80000000u);
}
__device__ inline float val_of(unsigned k){
  unsigned u = (k & 0x80000000u) ? (k & 0x7FFFFFFFu) : ~k;
  return __uint_as_float(u);
}

// ---------------- zero pads ----------------
__global__ void k_zero(uint4* p, int n4){
  int i = blockIdx.x*blockDim.x + threadIdx.x;
  if (i < n4) p[i] = make_uint4(0u,0u,0u,0u);
}

// ---------------- convert x (fp32) -> bf16 ----------------
__global__ __launch_bounds__(256) void k_x2b(const float4* __restrict__ x, ushort_t* __restrict__ xb){
  int i = blockIdx.x*blockDim.x + threadIdx.x;   // 524288 float4s
  float4 v = x[i];
  ushort_t* d = xb + (size_t)i*4;
  d[0]=f2b(v.x); d[1]=f2b(v.y); d[2]=f2b(v.z); d[3]=f2b(v.w);
}

// ---------------- transpose+convert 1024x1024 fp32 -> bf16 (4 matrices) ----------------
__global__ __launch_bounds__(256) void k_transpose(const float* w0, const float* w1,
                                                   const float* w2, const float* w3,
                                                   ushort_t* outw){
  const float* src = blockIdx.z==0?w0: blockIdx.z==1?w1: blockIdx.z==2?w2: w3;
  ushort_t* dst = outw + (size_t)blockIdx.z*1024*1024;
  __shared__ float t[64][65];
  int tid = threadIdx.x;
  int bx = blockIdx.x*64, by = blockIdx.y*64;
  #pragma unroll
  for (int p=0;p<16;p++){
    int idx = tid + p*256; int r = idx>>6, c = idx&63;
    t[r][c] = src[(size_t)(by + r)*1024 + bx + c];
  }
  __syncthreads();
  #pragma unroll
  for (int p=0;p<16;p++){
    int idx = tid + p*256; int a = idx>>6, c2 = idx&63;
    dst[(size_t)(bx + a)*1024 + by + c2] = f2b(t[c2][a]);
  }
}

// ---------------- QKV projection GEMM + fused rotary/l2norm epilogue ----------------
// nt = blockIdx.y: 0..47 -> which = nt>>4 (0=q,1=k,2=v), head h = nt&15.
__global__ __launch_bounds__(256) void k_qkv(const ushort_t* __restrict__ xb,
                                             const ushort_t* __restrict__ wt,
                                             const float* __restrict__ rpe,
                                             ushort_t* __restrict__ Qn,
                                             ushort_t* __restrict__ Kn,
                                             ushort_t* __restrict__ Vt){
  __shared__ __attribute__((aligned(16))) ushort_t As[64*32];
  __shared__ __attribute__((aligned(16))) ushort_t Bs[64*32];
  int tid = threadIdx.x;
  int m0 = blockIdx.x*64;
  int nt = blockIdx.y;
  const ushort_t* wsel = wt + (size_t)(nt>>4)*1024*1024;
  int c0 = (nt&15)*64;
  int w = tid>>6, lane = tid&63, n15 = lane&15, quad = lane>>4;
  int r = tid>>2, seg = tid&3;
  f32x4 acc[4];
  #pragma unroll
  for (int t=0;t<4;t++) acc[t] = (f32x4){0.f,0.f,0.f,0.f};
  for (int k0=0;k0<1024;k0+=32){
    __syncthreads();
    gld16(xb   + (size_t)(m0 + r)*1024 + k0 + seg*8, (void*)(As + tid*8));
    gld16(wsel + (size_t)(c0 + r)*1024 + k0 + seg*8, (void*)(Bs + tid*8));
    __builtin_amdgcn_s_waitcnt(0);
    __syncthreads();
    short8 a = *(const short8*)(As + (w*16 + n15)*32 + quad*8);
    #pragma unroll
    for (int t=0;t<4;t++){
      short8 b = *(const short8*)(Bs + (t*16 + n15)*32 + quad*8);
      acc[t] = __builtin_amdgcn_mfma_f32_16x16x32_bf16(a, b, acc[t], 0,0,0);
    }
  }
  // ---- fused epilogue: rotary (+ l2norm for q/k), direct layout stores ----
  int which = nt >> 4, h = nt & 15;
  int rowbase = m0 + w*16 + quad*4;     // global row (b*1024+n)
  int b = rowbase >> 10;
  float val[4][4];                      // [t][rr]
  #pragma unroll
  for (int rr=0; rr<4; rr++){
    int n = (rowbase + rr) & 1023;
    float f0 = rpe[n*ROTD + n15];
    float f1 = rpe[n*ROTD + 16 + n15];
    float c0r = __cosf(f0), s0r = __sinf(f0);
    float c1r = __cosf(f1), s1r = __sinf(f1);
    val[0][rr] = acc[0][rr]*c0r - acc[1][rr]*s0r;   // d<16: x*cos - x[d+16]*sin
    val[1][rr] = acc[1][rr]*c1r + acc[0][rr]*s1r;   // 16<=d<32: x*cos + x[d-16]*sin
    val[2][rr] = acc[2][rr];
    val[3][rr] = acc[3][rr];
  }
  if (which < 2){
    #pragma unroll
    for (int rr=0; rr<4; rr++){
      float ss = val[0][rr]*val[0][rr] + val[1][rr]*val[1][rr]
               + val[2][rr]*val[2][rr] + val[3][rr]*val[3][rr];
      #pragma unroll
      for (int off=1; off<16; off<<=1) ss += __shfl_xor(ss, off);
      float sc = 1.f / fmaxf(sqrtf(ss), 1e-12f);
      int n = (rowbase + rr) & 1023;
      if (which == 0){
        ushort_t* dst = Qn + ((size_t)(b*16+h)*NSEQ + n)*64;
        #pragma unroll
        for (int t=0;t<4;t++) dst[t*16 + n15] = f2b(val[t][rr]*sc);
      } else {
        ushort_t* dst = Kn + ((size_t)(b*16+h)*JP2 + (n+2))*64;
        #pragma unroll
        for (int t=0;t<4;t++) dst[t*16 + n15] = f2b(val[t][rr]*sc);
      }
    }
  } else {
    #pragma unroll
    for (int rr=0; rr<4; rr++){
      int n = (rowbase + rr) & 1023;
      #pragma unroll
      for (int t=0;t<4;t++){
        int d = t*16 + n15;
        Vt[((size_t)(b*16+h)*64 + d)*JP + (n+2)] = f2b(val[t][rr]);
      }
    }
  }
}

// ---------------- memory slots ----------------
__global__ void k_mem(const float* __restrict__ mem_k, const float* __restrict__ mem_v,
                      ushort_t* __restrict__ Kn, ushort_t* __restrict__ Vt){
  int tid = threadIdx.x;
  int d = tid & 63;
  int sub = tid >> 6;   // wave id 0..3
  for (int p=0; p<8; p++){
    int pp = p*4 + sub; int h = pp >> 1, m = pp & 1;
    float kv = mem_k[(h*2+m)*64 + d];
    float ss = kv*kv;
    #pragma unroll
    for (int off=1; off<64; off<<=1) ss += __shfl_xor(ss, off);
    float sc = 1.f/fmaxf(sqrtf(ss), 1e-12f);
    ushort_t kb = f2b(kv*sc);
    ushort_t vb = f2b(mem_v[(h*2+m)*64 + d]);
    for (int b=0;b<2;b++){
      Kn[((size_t)(b*16+h)*JP2 + m)*64 + d] = kb;
      Vt[((size_t)(b*16+h)*64 + d)*JP + m] = vb;
    }
  }
}

// ---------------- dots = 10 * Qn . Kn^T -> pre (d_out, fp32) ----------------
__global__ __launch_bounds__(256) void k_dots(const ushort_t* __restrict__ Qn,
        const ushort_t* __restrict__ Kn, float* __restrict__ pre){
  __shared__ __attribute__((aligned(16))) ushort_t As[64*64];
  __shared__ __attribute__((aligned(16))) ushort_t Bs[64*64];
  int tid = threadIdx.x;
  int m0 = blockIdx.x*64;
  int n0 = blockIdx.y*64;          // within JP2
  int bh = blockIdx.z;
  const ushort_t* A  = Qn + (size_t)bh*NSEQ*64 + (size_t)m0*64;
  const ushort_t* Bb = Kn + (size_t)bh*JP2*64 + (size_t)n0*64;
  int w = tid>>6, lane = tid&63, n15 = lane&15, quad = lane>>4;
  gld16(A  + tid*8,        (void*)(As + tid*8));
  gld16(A  + 2048 + tid*8, (void*)(As + 2048 + tid*8));
  gld16(Bb + tid*8,        (void*)(Bs + tid*8));
  gld16(Bb + 2048 + tid*8, (void*)(Bs + 2048 + tid*8));
  __builtin_amdgcn_s_waitcnt(0);
  __syncthreads();
  f32x4 acc[4];
  #pragma unroll
  for (int t=0;t<4;t++) acc[t] = (f32x4){0.f,0.f,0.f,0.f};
  #pragma unroll
  for (int kq=0;kq<2;kq++){
    short8 a = *(const short8*)(As + (w*16+n15)*64 + kq*32 + quad*8);
    #pragma unroll
    for (int t=0;t<4;t++){
      short8 b = *(const short8*)(Bs + (t*16+n15)*64 + kq*32 + quad*8);
      acc[t] = __builtin_amdgcn_mfma_f32_16x16x32_bf16(a, b, acc[t], 0,0,0);
    }
  }
  int rowbase = m0 + w*16 + quad*4;
  #pragma unroll
  for (int t=0;t<4;t++){
    #pragma unroll
    for (int rr=0;rr<4;rr++){
      int col = n0 + t*16 + n15;
      if (col < JCOL)
        pre[((size_t)bh*NSEQ + rowbase+rr)*JCOL + col] = acc[t][rr]*10.f;
    }
  }
}

// ---------------- th_pre mix + mask + top64 + softmax + th_post mix ----------------
// Rewrite: single launch, 256-col chunks (NCH=5), keys-only register state,
// gld16 staging, b128 vectorized mixes, transposed phase-5, <=64 VGPR target.
__global__ __launch_bounds__(1024, 8) void k_mixsoft(const float* __restrict__ pre,
        float* __restrict__ post, ushort_t* __restrict__ AM,
        const float* __restrict__ th_pre, const float* __restrict__ th_post){
  constexpr int NCH = 5;                 // 5 x 256 = 1280 cols capacity
  __shared__ __attribute__((aligned(16))) float S[16*1280];   // 80 KB -> 2 blocks/CU
  int tid  = threadIdx.x;
  int lane = tid & 63, wv = tid >> 6;    // wave wv owns head-row wv
  int blk = blockIdx.x;
  int b = blk >> 10, i = blk & 1023;
  int vend  = i + 3;                      // valid cols [0, vend)
  int rmaxC = (vend + 255) >> 8;          // active 256-col chunks (block-uniform)

  // ---- phase 1: stage row wv (chunk-granular) via global_load_lds x16B ----
  size_t rowoff = (size_t)(b*16 + wv)*NSEQ + i;
  const float* src = pre + rowoff*JCOL;
  float* Srow = S + wv*1280;
  for (int r = 0; r < rmaxC; r++)
    gld16(src + r*256 + lane*4, (void*)(Srow + r*256 + lane*4));
  __builtin_amdgcn_s_waitcnt(0);
  __syncthreads();

  // ---- phase 2: th_pre mix -> sortable keys (b128 LDS reads, 4 cols/lane) ----
  int h16 = __builtin_amdgcn_readfirstlane(wv) * 16;
  float TPr[16];
  #pragma unroll
  for (int g=0; g<16; g++) TPr[g] = th_pre[h16 + g];

  unsigned kr[NCH][4];
  #pragma unroll
  for (int r=0;r<NCH;r++){ kr[r][0]=0x00800000u; kr[r][1]=0x00800000u;
                           kr[r][2]=0x00800000u; kr[r][3]=0x00800000u; }  // key_of(MASKV)
  #pragma unroll
  for (int r=0;r<NCH;r++) if (r < rmaxC){
    int j0 = r*256 + lane*4;
    f32x4 a = (f32x4){0.f,0.f,0.f,0.f};
    #pragma unroll
    for (int g=0; g<16; g++){
      f32x4 sv = *(const f32x4*)(S + g*1280 + j0);
      a += sv * TPr[g];
    }
    #pragma unroll
    for (int c=0;c<4;c++) if (j0 + c < vend) kr[r][c] = key_of(a[c]);
  }
  __syncthreads();   // all phase-2 S reads done; S reused for post stash below

  // ---- phase 3: exact top-64 threshold, 2 bits/iter ----
  unsigned T = 0;
  for (int it=15; it>=0; --it){
    unsigned b1 = 1u << (2*it+1), b0 = 1u << (2*it);
    unsigned t3 = T|b1|b0, t2 = T|b1, t1 = T|b0;
    int c3=0, c2=0, c1=0;
    #pragma unroll
    for (int r=0;r<NCH;r++) if (r < rmaxC){
      #pragma unroll
      for (int c=0;c<4;c++){
        unsigned kk = kr[r][c];
        c3 += __popcll(__ballot(kk >= t3));
        c2 += __popcll(__ballot(kk >= t2));
        c1 += __popcll(__ballot(kk >= t1));
      }
    }
    T = (c3>=64) ? t3 : (c2>=64) ? t2 : (c1>=64) ? t1 : T;
  }
  // row max from keys (order-preserving)
  unsigned km = 0u;
  #pragma unroll
  for (int r=0;r<NCH;r++){
    #pragma unroll
    for (int c=0;c<4;c++){ unsigned kk = kr[r][c]; km = kk > km ? kk : km; }
  }
  #pragma unroll
  for (int off=32; off>=1; off>>=1){ unsigned o = __shfl_xor(km, off); km = o > km ? o : km; }
  float mx = val_of(km);
  float s = 0.f;
  #pragma unroll
  for (int r=0;r<NCH;r++) if (r < rmaxC){
    #pragma unroll
    for (int c=0;c<4;c++){
      unsigned kk = kr[r][c];
      if (kk >= T) s += __expf(val_of(kk) - mx);
    }
  }
  #pragma unroll
  for (int off=32; off>=1; off>>=1) s += __shfl_xor(s, off);
  float inv = 1.f / s;

  // ---- phase 4: write post row wv + stash p into S (f32x4) ----
  float* drow = post + rowoff*JCOL;
  #pragma unroll
  for (int r=0;r<NCH;r++) if (r < rmaxC){
    int j0 = r*256 + lane*4;
    f32x4 p;
    #pragma unroll
    for (int c=0;c<4;c++){
      unsigned kk = kr[r][c];
      float ev = (kk >= T) ? __expf(val_of(kk) - mx) : 0.f;  // masked cols -> exp(-huge)=0
      p[c] = ev * inv;
    }
    *(f32x4*)(Srow + j0) = p;
    if (j0 + 3 < JCOL){
      *(f32x2*)(drow + j0)     = (f32x2){p[0], p[1]};
      *(f32x2*)(drow + j0 + 2) = (f32x2){p[2], p[3]};
    } else {
      #pragma unroll
      for (int c=0;c<4;c++) if (j0 + c < JCOL) drow[j0+c] = p[c];
    }
  }
  for (int j = rmaxC*256 + lane; j < JCOL; j += 64) drow[j] = 0.f;
  __syncthreads();

  // ---- phase 5: th_post mix, transposed: wave = (h-pair, chunk-half) ----
  int hp = __builtin_amdgcn_readfirstlane(wv >> 1);   // 0..7
  int cq = __builtin_amdgcn_readfirstlane(wv & 1);    // 0..1
  float tq0[16], tq1[16];
  #pragma unroll
  for (int g=0; g<16; g++){
    tq0[g] = th_post[(hp*2  )*16 + g];
    tq1[g] = th_post[(hp*2+1)*16 + g];
  }
  ushort_t* am0 = AM + ((size_t)(b*16 + hp*2  )*NSEQ + i)*JP;
  ushort_t* am1 = AM + ((size_t)(b*16 + hp*2+1)*NSEQ + i)*JP;
  for (int r = cq; r < rmaxC; r += 2){
    int j0 = r*256 + lane*4;
    f32x4 a0 = (f32x4){0.f,0.f,0.f,0.f};
    f32x4 a1 = (f32x4){0.f,0.f,0.f,0.f};
    #pragma unroll
    for (int g=0; g<16; g++){
      f32x4 sv = *(const f32x4*)(S + g*1280 + j0);
      a0 += sv * tq0[g];
      a1 += sv * tq1[g];
    }
    if (j0 + 3 < JP){
      short4v v0 = (short4v){(short)f2b(a0[0]),(short)f2b(a0[1]),(short)f2b(a0[2]),(short)f2b(a0[3])};
      short4v v1 = (short4v){(short)f2b(a1[0]),(short)f2b(a1[1]),(short)f2b(a1[2]),(short)f2b(a1[3])};
      *(short4v*)(am0 + j0) = v0;
      *(short4v*)(am1 + j0) = v1;
    } else {
      #pragma unroll
      for (int c=0;c<4;c++) if (j0 + c < JP){
        am0[j0+c] = f2b(a0[c]);
        am1[j0+c] = f2b(a1[c]);
      }
    }
  }
  // AM tail zeros, wave-per-row mapping (disjoint from chunk region)
  {
    ushort_t* amw = AM + ((size_t)(b*16 + wv)*NSEQ + i)*JP;
    for (int j = rmaxC*256 + lane; j < JP; j += 64) amw[j] = 0;
  }
}

// ---------------- PV: O1 = AM . Vt^T ----------------
__global__ __launch_bounds__(256) void k_pv(const ushort_t* __restrict__ AM,
        const ushort_t* __restrict__ Vt, ushort_t* __restrict__ O1){
  __shared__ __attribute__((aligned(16))) ushort_t As[64*32];
  __shared__ __attribute__((aligned(16))) ushort_t Bs[64*32];
  int tid = threadIdx.x;
  int m0 = blockIdx.x*64;
  int bh = blockIdx.y;
  const ushort_t* Ab = AM + (size_t)bh*NSEQ*JP + (size_t)m0*JP;
  const ushort_t* Bb = Vt + (size_t)bh*64*JP;
  int w=tid>>6, lane=tid&63, n15=lane&15, quad=lane>>4;
  int r=tid>>2, seg=tid&3;
  f32x4 acc[4];
  #pragma unroll
  for (int t=0;t<4;t++) acc[t] = (f32x4){0.f,0.f,0.f,0.f};
  for (int k0=0;k0<JP;k0+=32){
    __syncthreads();
    gld16(Ab + (size_t)r*JP + k0 + seg*8, (void*)(As + tid*8));
    gld16(Bb + (size_t)r*JP + k0 + seg*8, (void*)(Bs + tid*8));
    __builtin_amdgcn_s_waitcnt(0);
    __syncthreads();
    short8 a = *(const short8*)(As + (w*16+n15)*32 + quad*8);
    #pragma unroll
    for (int t=0;t<4;t++){
      short8 b = *(const short8*)(Bs + (t*16+n15)*32 + quad*8);
      acc[t] = __builtin_amdgcn_mfma_f32_16x16x32_bf16(a, b, acc[t], 0,0,0);
    }
  }
  int b_ = bh>>4, h_ = bh&15;
  int rowbase = m0 + w*16 + quad*4;
  #pragma unroll
  for (int t=0;t<4;t++)
    #pragma unroll
    for (int rr=0;rr<4;rr++)
      O1[((size_t)b_*NSEQ + rowbase+rr)*1024 + h_*64 + t*16 + n15] = f2b(acc[t][rr]);
}

// ---------------- out = O1 . WoT^T (fp32 out) ----------------
__global__ __launch_bounds__(256) void k_outproj(const ushort_t* __restrict__ o1,
        const ushort_t* __restrict__ wot, float* __restrict__ outp){
  __shared__ __attribute__((aligned(16))) ushort_t As[64*32];
  __shared__ __attribute__((aligned(16))) ushort_t Bs[64*32];
  int tid = threadIdx.x;
  int m0 = blockIdx.x*64;
  int n0 = blockIdx.y*64;
  int w = tid>>6, lane = tid&63, n15 = lane&15, quad = lane>>4;
  int r = tid>>2, seg = tid&3;
  f32x4 acc[4];
  #pragma unroll
  for (int t=0;t<4;t++) acc[t] = (f32x4){0.f,0.f,0.f,0.f};
  for (int k0=0;k0<1024;k0+=32){
    __syncthreads();
    gld16(o1  + (size_t)(m0 + r)*1024 + k0 + seg*8, (void*)(As + tid*8));
    gld16(wot + (size_t)(n0 + r)*1024 + k0 + seg*8, (void*)(Bs + tid*8));
    __builtin_amdgcn_s_waitcnt(0);
    __syncthreads();
    short8 a = *(const short8*)(As + (w*16 + n15)*32 + quad*8);
    #pragma unroll
    for (int t=0;t<4;t++){
      short8 b = *(const short8*)(Bs + (t*16 + n15)*32 + quad*8);
      acc[t] = __builtin_amdgcn_mfma_f32_16x16x32_bf16(a, b, acc[t], 0,0,0);
    }
  }
  int rowbase = m0 + w*16 + quad*4;
  #pragma unroll
  for (int t=0;t<4;t++)
    #pragma unroll
    for (int rr=0;rr<4;rr++)
      outp[(size_t)(rowbase+rr)*1024 + n0 + t*16 + n15] = acc[t][rr];
}

extern "C" void kernel_launch(void* const* d_in, const int* in_sizes, int n_in,
                              void* d_out, int out_size, void* d_ws, size_t ws_size,
                              hipStream_t stream){
  const float* x   = (const float*)d_in[0];
  const float* rpe = (const float*)d_in[1];
  const float* Wq  = (const float*)d_in[2];
  const float* Wk  = (const float*)d_in[3];
  const float* Wv  = (const float*)d_in[4];
  const float* Wo  = (const float*)d_in[5];
  const float* mk  = (const float*)d_in[6];
  const float* mv  = (const float*)d_in[7];
  const float* thp = (const float*)d_in[8];
  const float* thq = (const float*)d_in[9];
  char* ws = (char*)d_ws;
  ushort_t* AM = (ushort_t*)(ws + 0);              // 2*16*1024*1056 bf16 = 69.2 MB
  ushort_t* Qn = (ushort_t*)(ws + 69206016);       // 4.19 MB
  ushort_t* Kn = (ushort_t*)(ws + 73400320);       // 4.46 MB (rows padded to 1088)
  ushort_t* Vt = (ushort_t*)(ws + 77856768);       // 4.33 MB (cols padded to 1056)
  ushort_t* O1 = (ushort_t*)(ws + 82182144);       // 4.19 MB
  ushort_t* WT = (ushort_t*)(ws + 86376448);       // 4 x 2.10 MB transposed bf16 weights
  ushort_t* Xb = (ushort_t*)(ws + 94765056);       // 4.19 MB bf16 x
  float* out0 = (float*)d_out;
  float* pre  = out0 + 2097152;
  float* post = pre + 33619968;

  k_zero<<<2144, 256, 0, stream>>>((uint4*)Kn, 548864);            // Kn+Vt contiguous
  k_x2b<<<2048, 256, 0, stream>>>((const float4*)x, Xb);
  k_transpose<<<dim3(16,16,4), 256, 0, stream>>>(Wq, Wk, Wv, Wo, WT);
  k_qkv<<<dim3(32,48), 256, 0, stream>>>(Xb, WT, rpe, Qn, Kn, Vt);
  k_mem<<<1, 256, 0, stream>>>(mk, mv, Kn, Vt);
  k_dots<<<dim3(16,17,32), 256, 0, stream>>>(Qn, Kn, pre);
  k_mixsoft<<<2048, 1024, 0, stream>>>(pre, post, AM, thp, thq);
  k_pv<<<dim3(16,32), 256, 0, stream>>>(AM, Vt, O1);
  k_outproj<<<dim3(32,16), 256, 0, stream>>>(O1, WT + 3*1048576, out0);
}

// Round 2
// 497.195 us; speedup vs baseline: 1.2322x; 1.0956x over previous
//
#include <hip/hip_runtime.h>
#include <stdint.h>

#define HN 16
#define DHD 64
#define NSEQ 1024
#define JCOL 1026
#define JP 1056   // PV k-pad (mult of 32)
#define JP2 1088  // dots n-pad (mult of 64)
#define ROTD 32
#define MASKV -3.402823466e+38f

typedef unsigned short ushort_t;
typedef __attribute__((ext_vector_type(8))) short short8;
typedef __attribute__((ext_vector_type(4))) short short4v;
typedef __attribute__((ext_vector_type(4))) float f32x4;
typedef __attribute__((ext_vector_type(2))) float f32x2;

__device__ inline ushort_t f2b(float f){ union{float f; unsigned int i;} v; v.f=f; unsigned x=v.i;
  return (ushort_t)((x + 0x7FFFu + ((x>>16)&1u))>>16); }

__device__ inline void gld16(const void* g, void* l){
  __builtin_amdgcn_global_load_lds((const __attribute__((address_space(1))) void*)g,
                                   (__attribute__((address_space(3))) void*)l, 16, 0, 0);
}

// order-preserving sortable key <-> float (invertible)
__device__ inline unsigned key_of(float f){
  unsigned u = __float_as_uint(f);
  return (u & 0x80000000u) ? ~u : (u | 0x80000000u);
}
__device__ inline float val_of(unsigned k){
  unsigned u = (k & 0x80000000u) ? (k & 0x7FFFFFFFu) : ~k;
  return __uint_as_float(u);
}

// ---- wave64 reductions via DPP (pure VALU: no SALU popc chains, no LDS pipe) ----
// row_shr:1/2/4/8 then row_bcast:15 (rows 1,3), row_bcast:31 (rows 2,3); total in lane 63.
__device__ inline int dpp_add_i(int x){
  x += __builtin_amdgcn_update_dpp(0, x, 0x111, 0xf, 0xf, true);
  x += __builtin_amdgcn_update_dpp(0, x, 0x112, 0xf, 0xf, true);
  x += __builtin_amdgcn_update_dpp(0, x, 0x114, 0xf, 0xf, true);
  x += __builtin_amdgcn_update_dpp(0, x, 0x118, 0xf, 0xf, true);
  x += __builtin_amdgcn_update_dpp(0, x, 0x142, 0xa, 0xf, true);
  x += __builtin_amdgcn_update_dpp(0, x, 0x143, 0xc, 0xf, true);
  return __builtin_amdgcn_readlane(x, 63);
}
__device__ inline float dpp_add_f(float x){
  int xi;
  xi = __builtin_amdgcn_update_dpp(0, __float_as_int(x), 0x111, 0xf, 0xf, true); x += __int_as_float(xi);
  xi = __builtin_amdgcn_update_dpp(0, __float_as_int(x), 0x112, 0xf, 0xf, true); x += __int_as_float(xi);
  xi = __builtin_amdgcn_update_dpp(0, __float_as_int(x), 0x114, 0xf, 0xf, true); x += __int_as_float(xi);
  xi = __builtin_amdgcn_update_dpp(0, __float_as_int(x), 0x118, 0xf, 0xf, true); x += __int_as_float(xi);
  xi = __builtin_amdgcn_update_dpp(0, __float_as_int(x), 0x142, 0xa, 0xf, true); x += __int_as_float(xi);
  xi = __builtin_amdgcn_update_dpp(0, __float_as_int(x), 0x143, 0xc, 0xf, true); x += __int_as_float(xi);
  return __int_as_float(__builtin_amdgcn_readlane(__float_as_int(x), 63));
}
__device__ inline unsigned dpp_max_u(unsigned x){
  unsigned t;
  t = (unsigned)__builtin_amdgcn_update_dpp(0, (int)x, 0x111, 0xf, 0xf, true); x = x > t ? x : t;
  t = (unsigned)__builtin_amdgcn_update_dpp(0, (int)x, 0x112, 0xf, 0xf, true); x = x > t ? x : t;
  t = (unsigned)__builtin_amdgcn_update_dpp(0, (int)x, 0x114, 0xf, 0xf, true); x = x > t ? x : t;
  t = (unsigned)__builtin_amdgcn_update_dpp(0, (int)x, 0x118, 0xf, 0xf, true); x = x > t ? x : t;
  t = (unsigned)__builtin_amdgcn_update_dpp(0, (int)x, 0x142, 0xa, 0xf, true); x = x > t ? x : t;
  t = (unsigned)__builtin_amdgcn_update_dpp(0, (int)x, 0x143, 0xc, 0xf, true); x = x > t ? x : t;
  return (unsigned)__builtin_amdgcn_readlane((int)x, 63);
}

// ---------------- zero pads ----------------
__global__ void k_zero(uint4* p, int n4){
  int i = blockIdx.x*blockDim.x + threadIdx.x;
  if (i < n4) p[i] = make_uint4(0u,0u,0u,0u);
}

// ---------------- convert x (fp32) -> bf16 ----------------
__global__ __launch_bounds__(256) void k_x2b(const float4* __restrict__ x, ushort_t* __restrict__ xb){
  int i = blockIdx.x*blockDim.x + threadIdx.x;   // 524288 float4s
  float4 v = x[i];
  ushort_t* d = xb + (size_t)i*4;
  d[0]=f2b(v.x); d[1]=f2b(v.y); d[2]=f2b(v.z); d[3]=f2b(v.w);
}

// ---------------- transpose+convert 1024x1024 fp32 -> bf16 (4 matrices) ----------------
__global__ __launch_bounds__(256) void k_transpose(const float* w0, const float* w1,
                                                   const float* w2, const float* w3,
                                                   ushort_t* outw){
  const float* src = blockIdx.z==0?w0: blockIdx.z==1?w1: blockIdx.z==2?w2: w3;
  ushort_t* dst = outw + (size_t)blockIdx.z*1024*1024;
  __shared__ float t[64][65];
  int tid = threadIdx.x;
  int bx = blockIdx.x*64, by = blockIdx.y*64;
  #pragma unroll
  for (int p=0;p<16;p++){
    int idx = tid + p*256; int r = idx>>6, c = idx&63;
    t[r][c] = src[(size_t)(by + r)*1024 + bx + c];
  }
  __syncthreads();
  #pragma unroll
  for (int p=0;p<16;p++){
    int idx = tid + p*256; int a = idx>>6, c2 = idx&63;
    dst[(size_t)(bx + a)*1024 + by + c2] = f2b(t[c2][a]);
  }
}

// ---------------- QKV projection GEMM (BM=128) + fused rotary/l2norm epilogue ----------------
// nt = blockIdx.y: 0..47 -> which = nt>>4 (0=q,1=k,2=v), head h = nt&15.
__global__ __launch_bounds__(256) void k_qkv(const ushort_t* __restrict__ xb,
                                             const ushort_t* __restrict__ wt,
                                             const float* __restrict__ rpe,
                                             ushort_t* __restrict__ Qn,
                                             ushort_t* __restrict__ Kn,
                                             ushort_t* __restrict__ Vt){
  __shared__ __attribute__((aligned(16))) ushort_t As[128*32];
  __shared__ __attribute__((aligned(16))) ushort_t Bs[64*32];
  int tid = threadIdx.x;
  int m0 = blockIdx.x*128;
  int nt = blockIdx.y;
  const ushort_t* wsel = wt + (size_t)(nt>>4)*1024*1024;
  int c0 = (nt&15)*64;
  int w = tid>>6, lane = tid&63, n15 = lane&15, quad = lane>>4;
  int r = tid>>2, seg = tid&3;
  f32x4 acc[2][4];
  #pragma unroll
  for (int m=0;m<2;m++)
    #pragma unroll
    for (int t=0;t<4;t++) acc[m][t] = (f32x4){0.f,0.f,0.f,0.f};
  for (int k0=0;k0<1024;k0+=32){
    __syncthreads();
    gld16(xb   + (size_t)(m0 + r)*1024 + k0 + seg*8,      (void*)(As + tid*8));
    gld16(xb   + (size_t)(m0 + 64 + r)*1024 + k0 + seg*8, (void*)(As + 2048 + tid*8));
    gld16(wsel + (size_t)(c0 + r)*1024 + k0 + seg*8,      (void*)(Bs + tid*8));
    __builtin_amdgcn_s_waitcnt(0);
    __syncthreads();
    #pragma unroll
    for (int m=0;m<2;m++){
      short8 a = *(const short8*)(As + (w*32 + m*16 + n15)*32 + quad*8);
      #pragma unroll
      for (int t=0;t<4;t++){
        short8 b = *(const short8*)(Bs + (t*16 + n15)*32 + quad*8);
        acc[m][t] = __builtin_amdgcn_mfma_f32_16x16x32_bf16(a, b, acc[m][t], 0,0,0);
      }
    }
  }
  // ---- fused epilogue: rotary (+ l2norm for q/k), direct layout stores ----
  int which = nt >> 4, h = nt & 15;
  #pragma unroll
  for (int m=0;m<2;m++){
    int rowbase = m0 + w*32 + m*16 + quad*4;     // global row (b*1024+n)
    int b = rowbase >> 10;
    float val[4][4];                      // [t][rr]
    #pragma unroll
    for (int rr=0; rr<4; rr++){
      int n = (rowbase + rr) & 1023;
      float f0 = rpe[n*ROTD + n15];
      float f1 = rpe[n*ROTD + 16 + n15];
      float c0r = __cosf(f0), s0r = __sinf(f0);
      float c1r = __cosf(f1), s1r = __sinf(f1);
      val[0][rr] = acc[m][0][rr]*c0r - acc[m][1][rr]*s0r;   // d<16: x*cos - x[d+16]*sin
      val[1][rr] = acc[m][1][rr]*c1r + acc[m][0][rr]*s1r;   // 16<=d<32: x*cos + x[d-16]*sin
      val[2][rr] = acc[m][2][rr];
      val[3][rr] = acc[m][3][rr];
    }
    if (which < 2){
      #pragma unroll
      for (int rr=0; rr<4; rr++){
        float ss = val[0][rr]*val[0][rr] + val[1][rr]*val[1][rr]
                 + val[2][rr]*val[2][rr] + val[3][rr]*val[3][rr];
        #pragma unroll
        for (int off=1; off<16; off<<=1) ss += __shfl_xor(ss, off);
        float sc = 1.f / fmaxf(sqrtf(ss), 1e-12f);
        int n = (rowbase + rr) & 1023;
        if (which == 0){
          ushort_t* dst = Qn + ((size_t)(b*16+h)*NSEQ + n)*64;
          #pragma unroll
          for (int t=0;t<4;t++) dst[t*16 + n15] = f2b(val[t][rr]*sc);
        } else {
          ushort_t* dst = Kn + ((size_t)(b*16+h)*JP2 + (n+2))*64;
          #pragma unroll
          for (int t=0;t<4;t++) dst[t*16 + n15] = f2b(val[t][rr]*sc);
        }
      }
    } else {
      #pragma unroll
      for (int rr=0; rr<4; rr++){
        int n = (rowbase + rr) & 1023;
        #pragma unroll
        for (int t=0;t<4;t++){
          int d = t*16 + n15;
          Vt[((size_t)(b*16+h)*64 + d)*JP + (n+2)] = f2b(val[t][rr]);
        }
      }
    }
  }
}

// ---------------- memory slots ----------------
__global__ void k_mem(const float* __restrict__ mem_k, const float* __restrict__ mem_v,
                      ushort_t* __restrict__ Kn, ushort_t* __restrict__ Vt){
  int tid = threadIdx.x;
  int d = tid & 63;
  int sub = tid >> 6;   // wave id 0..3
  for (int p=0; p<8; p++){
    int pp = p*4 + sub; int h = pp >> 1, m = pp & 1;
    float kv = mem_k[(h*2+m)*64 + d];
    float ss = kv*kv;
    #pragma unroll
    for (int off=1; off<64; off<<=1) ss += __shfl_xor(ss, off);
    float sc = 1.f/fmaxf(sqrtf(ss), 1e-12f);
    ushort_t kb = f2b(kv*sc);
    ushort_t vb = f2b(mem_v[(h*2+m)*64 + d]);
    for (int b=0;b<2;b++){
      Kn[((size_t)(b*16+h)*JP2 + m)*64 + d] = kb;
      Vt[((size_t)(b*16+h)*64 + d)*JP + m] = vb;
    }
  }
}

// ---------------- dots = 10 * Qn . Kn^T -> pre (d_out, fp32) ----------------
__global__ __launch_bounds__(256) void k_dots(const ushort_t* __restrict__ Qn,
        const ushort_t* __restrict__ Kn, float* __restrict__ pre){
  __shared__ __attribute__((aligned(16))) ushort_t As[64*64];
  __shared__ __attribute__((aligned(16))) ushort_t Bs[64*64];
  int tid = threadIdx.x;
  int m0 = blockIdx.x*64;
  int n0 = blockIdx.y*64;          // within JP2
  int bh = blockIdx.z;
  const ushort_t* A  = Qn + (size_t)bh*NSEQ*64 + (size_t)m0*64;
  const ushort_t* Bb = Kn + (size_t)bh*JP2*64 + (size_t)n0*64;
  int w = tid>>6, lane = tid&63, n15 = lane&15, quad = lane>>4;
  gld16(A  + tid*8,        (void*)(As + tid*8));
  gld16(A  + 2048 + tid*8, (void*)(As + 2048 + tid*8));
  gld16(Bb + tid*8,        (void*)(Bs + tid*8));
  gld16(Bb + 2048 + tid*8, (void*)(Bs + 2048 + tid*8));
  __builtin_amdgcn_s_waitcnt(0);
  __syncthreads();
  f32x4 acc[4];
  #pragma unroll
  for (int t=0;t<4;t++) acc[t] = (f32x4){0.f,0.f,0.f,0.f};
  #pragma unroll
  for (int kq=0;kq<2;kq++){
    short8 a = *(const short8*)(As + (w*16+n15)*64 + kq*32 + quad*8);
    #pragma unroll
    for (int t=0;t<4;t++){
      short8 b = *(const short8*)(Bs + (t*16+n15)*64 + kq*32 + quad*8);
      acc[t] = __builtin_amdgcn_mfma_f32_16x16x32_bf16(a, b, acc[t], 0,0,0);
    }
  }
  int rowbase = m0 + w*16 + quad*4;
  #pragma unroll
  for (int t=0;t<4;t++){
    #pragma unroll
    for (int rr=0;rr<4;rr++){
      int col = n0 + t*16 + n15;
      if (col < JCOL)
        pre[((size_t)bh*NSEQ + rowbase+rr)*JCOL + col] = acc[t][rr]*10.f;
    }
  }
}

// ---------------- th_pre mix + mask + top64 + softmax + th_post mix ----------------
// Phase 3 rewritten: 1-bit radix-select, per-lane VALU counting (no SALU popc),
// DPP wave reductions (no LDS pipe), exact early-exit at count==64, exp stashed in keys.
__global__ __launch_bounds__(1024, 8) void k_mixsoft(const float* __restrict__ pre,
        float* __restrict__ post, ushort_t* __restrict__ AM,
        const float* __restrict__ th_pre, const float* __restrict__ th_post){
  constexpr int NCH = 5;                 // 5 x 256 = 1280 cols capacity
  __shared__ __attribute__((aligned(16))) float S[16*1280];   // 80 KB -> 2 blocks/CU
  int tid  = threadIdx.x;
  int lane = tid & 63, wv = tid >> 6;    // wave wv owns head-row wv
  int blk = blockIdx.x;
  int b = blk >> 10, i = blk & 1023;
  int vend  = i + 3;                      // valid cols [0, vend)
  int rmaxC = (vend + 255) >> 8;          // active 256-col chunks (block-uniform)

  // ---- phase 1: stage row wv (chunk-granular) via global_load_lds x16B ----
  size_t rowoff = (size_t)(b*16 + wv)*NSEQ + i;
  const float* src = pre + rowoff*JCOL;
  float* Srow = S + wv*1280;
  for (int r = 0; r < rmaxC; r++)
    gld16(src + r*256 + lane*4, (void*)(Srow + r*256 + lane*4));
  __builtin_amdgcn_s_waitcnt(0);
  __syncthreads();

  // ---- phase 2: th_pre mix -> sortable keys (b128 LDS reads, 4 cols/lane) ----
  int h16 = __builtin_amdgcn_readfirstlane(wv) * 16;
  float TPr[16];
  #pragma unroll
  for (int g=0; g<16; g++) TPr[g] = th_pre[h16 + g];

  unsigned kr[NCH][4];
  #pragma unroll
  for (int r=0;r<NCH;r++){ kr[r][0]=0x00800000u; kr[r][1]=0x00800000u;
                           kr[r][2]=0x00800000u; kr[r][3]=0x00800000u; }  // key_of(MASKV)
  #pragma unroll
  for (int r=0;r<NCH;r++) if (r < rmaxC){
    int j0 = r*256 + lane*4;
    f32x4 a = (f32x4){0.f,0.f,0.f,0.f};
    #pragma unroll
    for (int g=0; g<16; g++){
      f32x4 sv = *(const f32x4*)(S + g*1280 + j0);
      a += sv * TPr[g];
    }
    #pragma unroll
    for (int c=0;c<4;c++) if (j0 + c < vend) kr[r][c] = key_of(a[c]);
  }
  __syncthreads();   // all phase-2 S reads done; S reused for post stash below

  // ---- phase 3: exact top-64 threshold, 1 bit/iter, VALU counting + DPP reduce ----
  unsigned T = 0;
  for (int bit=31; bit>=0; --bit){
    unsigned cand = T | (1u << bit);
    int lc = 0;
    #pragma unroll
    for (int r=0;r<NCH;r++) if (r < rmaxC){
      #pragma unroll
      for (int c=0;c<4;c++) lc += (kr[r][c] >= cand) ? 1 : 0;
    }
    int tot = dpp_add_i(lc);
    if (tot >= 64){
      T = cand;
      if (tot == 64) break;   // set {k >= cand} == top-64 set exactly
    }
  }
  // row max from keys (order-preserving)
  unsigned km = 0u;
  #pragma unroll
  for (int r=0;r<NCH;r++){
    #pragma unroll
    for (int c=0;c<4;c++){ unsigned kk = kr[r][c]; km = kk > km ? kk : km; }
  }
  km = dpp_max_u(km);
  float mx = val_of(km);
  float s = 0.f;
  #pragma unroll
  for (int r=0;r<NCH;r++) if (r < rmaxC){
    #pragma unroll
    for (int c=0;c<4;c++){
      unsigned kk = kr[r][c];
      float ev = (kk >= T) ? __expf(val_of(kk) - mx) : 0.f;  // masked -> exp(-huge)=0
      s += ev;
      kr[r][c] = __float_as_uint(ev);     // stash exp for phase 4
    }
  }
  s = dpp_add_f(s);
  float inv = 1.f / s;

  // ---- phase 4: write post row wv + stash p into S (f32x4) ----
  float* drow = post + rowoff*JCOL;
  #pragma unroll
  for (int r=0;r<NCH;r++) if (r < rmaxC){
    int j0 = r*256 + lane*4;
    f32x4 p;
    #pragma unroll
    for (int c=0;c<4;c++) p[c] = __uint_as_float(kr[r][c]) * inv;
    *(f32x4*)(Srow + j0) = p;
    if (j0 + 3 < JCOL){
      *(f32x2*)(drow + j0)     = (f32x2){p[0], p[1]};
      *(f32x2*)(drow + j0 + 2) = (f32x2){p[2], p[3]};
    } else {
      #pragma unroll
      for (int c=0;c<4;c++) if (j0 + c < JCOL) drow[j0+c] = p[c];
    }
  }
  for (int j = rmaxC*256 + lane; j < JCOL; j += 64) drow[j] = 0.f;
  __syncthreads();

  // ---- phase 5: th_post mix, transposed: wave = (h-pair, chunk-half) ----
  int hp = __builtin_amdgcn_readfirstlane(wv >> 1);   // 0..7
  int cq = __builtin_amdgcn_readfirstlane(wv & 1);    // 0..1
  float tq0[16], tq1[16];
  #pragma unroll
  for (int g=0; g<16; g++){
    tq0[g] = th_post[(hp*2  )*16 + g];
    tq1[g] = th_post[(hp*2+1)*16 + g];
  }
  ushort_t* am0 = AM + ((size_t)(b*16 + hp*2  )*NSEQ + i)*JP;
  ushort_t* am1 = AM + ((size_t)(b*16 + hp*2+1)*NSEQ + i)*JP;
  for (int r = cq; r < rmaxC; r += 2){
    int j0 = r*256 + lane*4;
    f32x4 a0 = (f32x4){0.f,0.f,0.f,0.f};
    f32x4 a1 = (f32x4){0.f,0.f,0.f,0.f};
    #pragma unroll
    for (int g=0; g<16; g++){
      f32x4 sv = *(const f32x4*)(S + g*1280 + j0);
      a0 += sv * tq0[g];
      a1 += sv * tq1[g];
    }
    if (j0 + 3 < JP){
      short4v v0 = (short4v){(short)f2b(a0[0]),(short)f2b(a0[1]),(short)f2b(a0[2]),(short)f2b(a0[3])};
      short4v v1 = (short4v){(short)f2b(a1[0]),(short)f2b(a1[1]),(short)f2b(a1[2]),(short)f2b(a1[3])};
      *(short4v*)(am0 + j0) = v0;
      *(short4v*)(am1 + j0) = v1;
    } else {
      #pragma unroll
      for (int c=0;c<4;c++) if (j0 + c < JP){
        am0[j0+c] = f2b(a0[c]);
        am1[j0+c] = f2b(a1[c]);
      }
    }
  }
  // AM tail zeros, wave-per-row mapping (disjoint from chunk region)
  {
    ushort_t* amw = AM + ((size_t)(b*16 + wv)*NSEQ + i)*JP;
    for (int j = rmaxC*256 + lane; j < JP; j += 64) amw[j] = 0;
  }
}

// ---------------- PV: O1 = AM . Vt^T ----------------
__global__ __launch_bounds__(256) void k_pv(const ushort_t* __restrict__ AM,
        const ushort_t* __restrict__ Vt, ushort_t* __restrict__ O1){
  __shared__ __attribute__((aligned(16))) ushort_t As[64*32];
  __shared__ __attribute__((aligned(16))) ushort_t Bs[64*32];
  int tid = threadIdx.x;
  int m0 = blockIdx.x*64;
  int bh = blockIdx.y;
  const ushort_t* Ab = AM + (size_t)bh*NSEQ*JP + (size_t)m0*JP;
  const ushort_t* Bb = Vt + (size_t)bh*64*JP;
  int w=tid>>6, lane=tid&63, n15=lane&15, quad=lane>>4;
  int r=tid>>2, seg=tid&3;
  f32x4 acc[4];
  #pragma unroll
  for (int t=0;t<4;t++) acc[t] = (f32x4){0.f,0.f,0.f,0.f};
  for (int k0=0;k0<JP;k0+=32){
    __syncthreads();
    gld16(Ab + (size_t)r*JP + k0 + seg*8, (void*)(As + tid*8));
    gld16(Bb + (size_t)r*JP + k0 + seg*8, (void*)(Bs + tid*8));
    __builtin_amdgcn_s_waitcnt(0);
    __syncthreads();
    short8 a = *(const short8*)(As + (w*16+n15)*32 + quad*8);
    #pragma unroll
    for (int t=0;t<4;t++){
      short8 b = *(const short8*)(Bs + (t*16+n15)*32 + quad*8);
      acc[t] = __builtin_amdgcn_mfma_f32_16x16x32_bf16(a, b, acc[t], 0,0,0);
    }
  }
  int b_ = bh>>4, h_ = bh&15;
  int rowbase = m0 + w*16 + quad*4;
  #pragma unroll
  for (int t=0;t<4;t++)
    #pragma unroll
    for (int rr=0;rr<4;rr++)
      O1[((size_t)b_*NSEQ + rowbase+rr)*1024 + h_*64 + t*16 + n15] = f2b(acc[t][rr]);
}

// ---------------- out = O1 . WoT^T (fp32 out, BM=128) ----------------
__global__ __launch_bounds__(256) void k_outproj(const ushort_t* __restrict__ o1,
        const ushort_t* __restrict__ wot, float* __restrict__ outp){
  __shared__ __attribute__((aligned(16))) ushort_t As[128*32];
  __shared__ __attribute__((aligned(16))) ushort_t Bs[64*32];
  int tid = threadIdx.x;
  int m0 = blockIdx.x*128;
  int n0 = blockIdx.y*64;
  int w = tid>>6, lane = tid&63, n15 = lane&15, quad = lane>>4;
  int r = tid>>2, seg = tid&3;
  f32x4 acc[2][4];
  #pragma unroll
  for (int m=0;m<2;m++)
    #pragma unroll
    for (int t=0;t<4;t++) acc[m][t] = (f32x4){0.f,0.f,0.f,0.f};
  for (int k0=0;k0<1024;k0+=32){
    __syncthreads();
    gld16(o1  + (size_t)(m0 + r)*1024 + k0 + seg*8,      (void*)(As + tid*8));
    gld16(o1  + (size_t)(m0 + 64 + r)*1024 + k0 + seg*8, (void*)(As + 2048 + tid*8));
    gld16(wot + (size_t)(n0 + r)*1024 + k0 + seg*8,      (void*)(Bs + tid*8));
    __builtin_amdgcn_s_waitcnt(0);
    __syncthreads();
    #pragma unroll
    for (int m=0;m<2;m++){
      short8 a = *(const short8*)(As + (w*32 + m*16 + n15)*32 + quad*8);
      #pragma unroll
      for (int t=0;t<4;t++){
        short8 b = *(const short8*)(Bs + (t*16 + n15)*32 + quad*8);
        acc[m][t] = __builtin_amdgcn_mfma_f32_16x16x32_bf16(a, b, acc[m][t], 0,0,0);
      }
    }
  }
  #pragma unroll
  for (int m=0;m<2;m++){
    int rowbase = m0 + w*32 + m*16 + quad*4;
    #pragma unroll
    for (int t=0;t<4;t++)
      #pragma unroll
      for (int rr=0;rr<4;rr++)
        outp[(size_t)(rowbase+rr)*1024 + n0 + t*16 + n15] = acc[m][t][rr];
  }
}

extern "C" void kernel_launch(void* const* d_in, const int* in_sizes, int n_in,
                              void* d_out, int out_size, void* d_ws, size_t ws_size,
                              hipStream_t stream){
  const float* x   = (const float*)d_in[0];
  const float* rpe = (const float*)d_in[1];
  const float* Wq  = (const float*)d_in[2];
  const float* Wk  = (const float*)d_in[3];
  const float* Wv  = (const float*)d_in[4];
  const float* Wo  = (const float*)d_in[5];
  const float* mk  = (const float*)d_in[6];
  const float* mv  = (const float*)d_in[7];
  const float* thp = (const float*)d_in[8];
  const float* thq = (const float*)d_in[9];
  char* ws = (char*)d_ws;
  ushort_t* AM = (ushort_t*)(ws + 0);              // 2*16*1024*1056 bf16 = 69.2 MB
  ushort_t* Qn = (ushort_t*)(ws + 69206016);       // 4.19 MB
  ushort_t* Kn = (ushort_t*)(ws + 73400320);       // 4.46 MB (rows padded to 1088)
  ushort_t* Vt = (ushort_t*)(ws + 77856768);       // 4.33 MB (cols padded to 1056)
  ushort_t* O1 = (ushort_t*)(ws + 82182144);       // 4.19 MB
  ushort_t* WT = (ushort_t*)(ws + 86376448);       // 4 x 2.10 MB transposed bf16 weights
  ushort_t* Xb = (ushort_t*)(ws + 94765056);       // 4.19 MB bf16 x
  float* out0 = (float*)d_out;
  float* pre  = out0 + 2097152;
  float* post = pre + 33619968;

  k_zero<<<2144, 256, 0, stream>>>((uint4*)Kn, 548864);            // Kn+Vt contiguous
  k_x2b<<<2048, 256, 0, stream>>>((const float4*)x, Xb);
  k_transpose<<<dim3(16,16,4), 256, 0, stream>>>(Wq, Wk, Wv, Wo, WT);
  k_qkv<<<dim3(16,48), 256, 0, stream>>>(Xb, WT, rpe, Qn, Kn, Vt);
  k_mem<<<1, 256, 0, stream>>>(mk, mv, Kn, Vt);
  k_dots<<<dim3(16,17,32), 256, 0, stream>>>(Qn, Kn, pre);
  k_mixsoft<<<2048, 1024, 0, stream>>>(pre, post, AM, thp, thq);
  k_pv<<<dim3(16,32), 256, 0, stream>>>(AM, Vt, O1);
  k_outproj<<<dim3(16,16), 256, 0, stream>>>(O1, WT + 3*1048576, out0);
}

// Round 4
// 482.554 us; speedup vs baseline: 1.2695x; 1.0303x over previous
//
#include <hip/hip_runtime.h>
#include <stdint.h>

#define HN 16
#define DHD 64
#define NSEQ 1024
#define JCOL 1026
#define JP 1056   // PV k-pad (mult of 32)
#define JP2 1088  // dots n-pad (mult of 64)
#define ROTD 32
#define MASKV -3.402823466e+38f

typedef unsigned short ushort_t;
typedef __attribute__((ext_vector_type(8))) short short8;
typedef __attribute__((ext_vector_type(4))) short short4v;
typedef __attribute__((ext_vector_type(4))) float f32x4;
typedef __attribute__((ext_vector_type(2))) float f32x2;

__device__ inline ushort_t f2b(float f){ union{float f; unsigned int i;} v; v.f=f; unsigned x=v.i;
  return (ushort_t)((x + 0x7FFFu + ((x>>16)&1u))>>16); }

__device__ inline void gld16(const void* g, void* l){
  __builtin_amdgcn_global_load_lds((const __attribute__((address_space(1))) void*)g,
                                   (__attribute__((address_space(3))) void*)l, 16, 0, 0);
}

// order-preserving sortable key <-> float (invertible)
__device__ inline unsigned key_of(float f){
  unsigned u = __float_as_uint(f);
  return (u & 0x80000000u) ? ~u : (u | 0x80000000u);
}
__device__ inline float val_of(unsigned k){
  unsigned u = (k & 0x80000000u) ? (k & 0x7FFFFFFFu) : ~k;
  return __uint_as_float(u);
}

// ---- wave64 reductions via DPP (pure VALU: no SALU popc chains, no LDS pipe) ----
__device__ inline int dpp_add_i(int x){
  x += __builtin_amdgcn_update_dpp(0, x, 0x111, 0xf, 0xf, true);
  x += __builtin_amdgcn_update_dpp(0, x, 0x112, 0xf, 0xf, true);
  x += __builtin_amdgcn_update_dpp(0, x, 0x114, 0xf, 0xf, true);
  x += __builtin_amdgcn_update_dpp(0, x, 0x118, 0xf, 0xf, true);
  x += __builtin_amdgcn_update_dpp(0, x, 0x142, 0xa, 0xf, true);
  x += __builtin_amdgcn_update_dpp(0, x, 0x143, 0xc, 0xf, true);
  return __builtin_amdgcn_readlane(x, 63);
}
__device__ inline float dpp_add_f(float x){
  int xi;
  xi = __builtin_amdgcn_update_dpp(0, __float_as_int(x), 0x111, 0xf, 0xf, true); x += __int_as_float(xi);
  xi = __builtin_amdgcn_update_dpp(0, __float_as_int(x), 0x112, 0xf, 0xf, true); x += __int_as_float(xi);
  xi = __builtin_amdgcn_update_dpp(0, __float_as_int(x), 0x114, 0xf, 0xf, true); x += __int_as_float(xi);
  xi = __builtin_amdgcn_update_dpp(0, __float_as_int(x), 0x118, 0xf, 0xf, true); x += __int_as_float(xi);
  xi = __builtin_amdgcn_update_dpp(0, __float_as_int(x), 0x142, 0xa, 0xf, true); x += __int_as_float(xi);
  xi = __builtin_amdgcn_update_dpp(0, __float_as_int(x), 0x143, 0xc, 0xf, true); x += __int_as_float(xi);
  return __int_as_float(__builtin_amdgcn_readlane(__float_as_int(x), 63));
}
__device__ inline unsigned dpp_max_u(unsigned x){
  unsigned t;
  t = (unsigned)__builtin_amdgcn_update_dpp(0, (int)x, 0x111, 0xf, 0xf, true); x = x > t ? x : t;
  t = (unsigned)__builtin_amdgcn_update_dpp(0, (int)x, 0x112, 0xf, 0xf, true); x = x > t ? x : t;
  t = (unsigned)__builtin_amdgcn_update_dpp(0, (int)x, 0x114, 0xf, 0xf, true); x = x > t ? x : t;
  t = (unsigned)__builtin_amdgcn_update_dpp(0, (int)x, 0x118, 0xf, 0xf, true); x = x > t ? x : t;
  t = (unsigned)__builtin_amdgcn_update_dpp(0, (int)x, 0x142, 0xa, 0xf, true); x = x > t ? x : t;
  t = (unsigned)__builtin_amdgcn_update_dpp(0, (int)x, 0x143, 0xc, 0xf, true); x = x > t ? x : t;
  return (unsigned)__builtin_amdgcn_readlane((int)x, 63);
}

// ---------------- merged preprocessing ----------------
// z<4: transpose+convert weight matrix z. z=4: x2b half 0 + Vt pad-col zero.
// z=5: x2b half 1 (+ block(0,0): mem-slot fill).
// Kn pad rows [1026,1088) are intentionally NOT zeroed: they feed only dots
// output cols >= JCOL which are never stored (MFMA cols are independent).
__global__ __launch_bounds__(256) void k_prep(const float* __restrict__ w0, const float* __restrict__ w1,
    const float* __restrict__ w2, const float* __restrict__ w3, ushort_t* __restrict__ outw,
    const float4* __restrict__ x, ushort_t* __restrict__ xb,
    const float* __restrict__ mem_k, const float* __restrict__ mem_v,
    ushort_t* __restrict__ Kn, ushort_t* __restrict__ Vt){
  __shared__ float t[64][65];
  int tid = threadIdx.x;
  int z = blockIdx.z;
  if (z < 4){
    const float* src = z==0?w0: z==1?w1: z==2?w2: w3;
    ushort_t* dst = outw + (size_t)z*1024*1024;
    int bx = blockIdx.x*64, by = blockIdx.y*64;
    #pragma unroll
    for (int p=0;p<16;p++){
      int idx = tid + p*256; int r = idx>>6, c = idx&63;
      t[r][c] = src[(size_t)(by + r)*1024 + bx + c];
    }
    __syncthreads();
    #pragma unroll
    for (int p=0;p<16;p++){
      int idx = tid + p*256; int a = idx>>6, c2 = idx&63;
      dst[(size_t)(bx + a)*1024 + by + c2] = f2b(t[c2][a]);
    }
  } else {
    int flat = (((z-4)*16 + blockIdx.y)*16 + blockIdx.x)*256 + tid;   // [0, 131072)
    #pragma unroll
    for (int p=0;p<4;p++){
      int i = flat + p*131072;
      float4 v = x[i];
      ushort_t* d = xb + (size_t)i*4;
      d[0]=f2b(v.x); d[1]=f2b(v.y); d[2]=f2b(v.z); d[3]=f2b(v.w);
    }
    if (z == 4){
      // zero Vt pad cols [1026,1056): 2048 rows x 30 cols; flat in [0,65536)=2048x32
      int c = flat & 31, row = flat >> 5;
      if (c < 30) Vt[(size_t)row*JP + 1026 + c] = 0;
    } else if (blockIdx.x==0 && blockIdx.y==0){
      // memory slots (l2norm'd K, raw V)
      int d = tid & 63, sub = tid >> 6;
      for (int p=0; p<8; p++){
        int pp = p*4 + sub; int h = pp >> 1, m = pp & 1;
        float kv = mem_k[(h*2+m)*64 + d];
        float ss = kv*kv;
        #pragma unroll
        for (int off=1; off<64; off<<=1) ss += __shfl_xor(ss, off);
        float sc = 1.f/fmaxf(sqrtf(ss), 1e-12f);
        ushort_t kb = f2b(kv*sc);
        ushort_t vb = f2b(mem_v[(h*2+m)*64 + d]);
        for (int b=0;b<2;b++){
          Kn[((size_t)(b*16+h)*JP2 + m)*64 + d] = kb;
          Vt[((size_t)(b*16+h)*64 + d)*JP + m] = vb;
        }
      }
    }
  }
}

// ---------------- QKV projection GEMM (BM=128) + fused rotary/l2norm epilogue ----------------
// nt = blockIdx.y: 0..47 -> which = nt>>4 (0=q,1=k,2=v), head h = nt&15.
__global__ __launch_bounds__(256) void k_qkv(const ushort_t* __restrict__ xb,
                                             const ushort_t* __restrict__ wt,
                                             const float* __restrict__ rpe,
                                             ushort_t* __restrict__ Qn,
                                             ushort_t* __restrict__ Kn,
                                             ushort_t* __restrict__ Vt){
  __shared__ __attribute__((aligned(16))) ushort_t As[128*32];
  __shared__ __attribute__((aligned(16))) ushort_t Bs[64*32];
  int tid = threadIdx.x;
  int m0 = blockIdx.x*128;
  int nt = blockIdx.y;
  const ushort_t* wsel = wt + (size_t)(nt>>4)*1024*1024;
  int c0 = (nt&15)*64;
  int w = tid>>6, lane = tid&63, n15 = lane&15, quad = lane>>4;
  int r = tid>>2, seg = tid&3;
  f32x4 acc[2][4];
  #pragma unroll
  for (int m=0;m<2;m++)
    #pragma unroll
    for (int t=0;t<4;t++) acc[m][t] = (f32x4){0.f,0.f,0.f,0.f};
  for (int k0=0;k0<1024;k0+=32){
    __syncthreads();
    gld16(xb   + (size_t)(m0 + r)*1024 + k0 + seg*8,      (void*)(As + tid*8));
    gld16(xb   + (size_t)(m0 + 64 + r)*1024 + k0 + seg*8, (void*)(As + 2048 + tid*8));
    gld16(wsel + (size_t)(c0 + r)*1024 + k0 + seg*8,      (void*)(Bs + tid*8));
    __builtin_amdgcn_s_waitcnt(0);
    __syncthreads();
    #pragma unroll
    for (int m=0;m<2;m++){
      short8 a = *(const short8*)(As + (w*32 + m*16 + n15)*32 + quad*8);
      #pragma unroll
      for (int t=0;t<4;t++){
        short8 b = *(const short8*)(Bs + (t*16 + n15)*32 + quad*8);
        acc[m][t] = __builtin_amdgcn_mfma_f32_16x16x32_bf16(a, b, acc[m][t], 0,0,0);
      }
    }
  }
  // ---- fused epilogue: rotary (+ l2norm for q/k), direct layout stores ----
  int which = nt >> 4, h = nt & 15;
  #pragma unroll
  for (int m=0;m<2;m++){
    int rowbase = m0 + w*32 + m*16 + quad*4;     // global row (b*1024+n)
    int b = rowbase >> 10;
    float val[4][4];                      // [t][rr]
    #pragma unroll
    for (int rr=0; rr<4; rr++){
      int n = (rowbase + rr) & 1023;
      float f0 = rpe[n*ROTD + n15];
      float f1 = rpe[n*ROTD + 16 + n15];
      float c0r = __cosf(f0), s0r = __sinf(f0);
      float c1r = __cosf(f1), s1r = __sinf(f1);
      val[0][rr] = acc[m][0][rr]*c0r - acc[m][1][rr]*s0r;   // d<16: x*cos - x[d+16]*sin
      val[1][rr] = acc[m][1][rr]*c1r + acc[m][0][rr]*s1r;   // 16<=d<32: x*cos + x[d-16]*sin
      val[2][rr] = acc[m][2][rr];
      val[3][rr] = acc[m][3][rr];
    }
    if (which < 2){
      #pragma unroll
      for (int rr=0; rr<4; rr++){
        float ss = val[0][rr]*val[0][rr] + val[1][rr]*val[1][rr]
                 + val[2][rr]*val[2][rr] + val[3][rr]*val[3][rr];
        #pragma unroll
        for (int off=1; off<16; off<<=1) ss += __shfl_xor(ss, off);
        float sc = 1.f / fmaxf(sqrtf(ss), 1e-12f);
        int n = (rowbase + rr) & 1023;
        if (which == 0){
          ushort_t* dst = Qn + ((size_t)(b*16+h)*NSEQ + n)*64;
          #pragma unroll
          for (int t=0;t<4;t++) dst[t*16 + n15] = f2b(val[t][rr]*sc);
        } else {
          ushort_t* dst = Kn + ((size_t)(b*16+h)*JP2 + (n+2))*64;
          #pragma unroll
          for (int t=0;t<4;t++) dst[t*16 + n15] = f2b(val[t][rr]*sc);
        }
      }
    } else {
      #pragma unroll
      for (int rr=0; rr<4; rr++){
        int n = (rowbase + rr) & 1023;
        #pragma unroll
        for (int t=0;t<4;t++){
          int d = t*16 + n15;
          Vt[((size_t)(b*16+h)*64 + d)*JP + (n+2)] = f2b(val[t][rr]);
        }
      }
    }
  }
}

// ---------------- dots = 10 * Qn . Kn^T -> pre (d_out, fp32) ----------------
__global__ __launch_bounds__(256) void k_dots(const ushort_t* __restrict__ Qn,
        const ushort_t* __restrict__ Kn, float* __restrict__ pre){
  __shared__ __attribute__((aligned(16))) ushort_t As[64*64];
  __shared__ __attribute__((aligned(16))) ushort_t Bs[64*64];
  int tid = threadIdx.x;
  int m0 = blockIdx.x*64;
  int n0 = blockIdx.y*64;          // within JP2
  int bh = blockIdx.z;
  const ushort_t* A  = Qn + (size_t)bh*NSEQ*64 + (size_t)m0*64;
  const ushort_t* Bb = Kn + (size_t)bh*JP2*64 + (size_t)n0*64;
  int w = tid>>6, lane = tid&63, n15 = lane&15, quad = lane>>4;
  gld16(A  + tid*8,        (void*)(As + tid*8));
  gld16(A  + 2048 + tid*8, (void*)(As + 2048 + tid*8));
  gld16(Bb + tid*8,        (void*)(Bs + tid*8));
  gld16(Bb + 2048 + tid*8, (void*)(Bs + 2048 + tid*8));
  __builtin_amdgcn_s_waitcnt(0);
  __syncthreads();
  f32x4 acc[4];
  #pragma unroll
  for (int t=0;t<4;t++) acc[t] = (f32x4){0.f,0.f,0.f,0.f};
  #pragma unroll
  for (int kq=0;kq<2;kq++){
    short8 a = *(const short8*)(As + (w*16+n15)*64 + kq*32 + quad*8);
    #pragma unroll
    for (int t=0;t<4;t++){
      short8 b = *(const short8*)(Bs + (t*16+n15)*64 + kq*32 + quad*8);
      acc[t] = __builtin_amdgcn_mfma_f32_16x16x32_bf16(a, b, acc[t], 0,0,0);
    }
  }
  int rowbase = m0 + w*16 + quad*4;
  #pragma unroll
  for (int t=0;t<4;t++){
    #pragma unroll
    for (int rr=0;rr<4;rr++){
      int col = n0 + t*16 + n15;
      if (col < JCOL)
        pre[((size_t)bh*NSEQ + rowbase+rr)*JCOL + col] = acc[t][rr]*10.f;
    }
  }
}

// ---------------- th_pre mix + mask + top64 + softmax + th_post mix ----------------
__global__ __launch_bounds__(1024, 8) void k_mixsoft(const float* __restrict__ pre,
        float* __restrict__ post, ushort_t* __restrict__ AM,
        const float* __restrict__ th_pre, const float* __restrict__ th_post){
  constexpr int NCH = 5;                 // 5 x 256 = 1280 cols capacity
  __shared__ __attribute__((aligned(16))) float S[16*1280];   // 80 KB -> 2 blocks/CU
  int tid  = threadIdx.x;
  int lane = tid & 63, wv = tid >> 6;    // wave wv owns head-row wv
  int blk = blockIdx.x;
  int b = blk >> 10, i = blk & 1023;
  int vend  = i + 3;                      // valid cols [0, vend)
  int rmaxC = (vend + 255) >> 8;          // active 256-col chunks (block-uniform)

  // ---- phase 1: stage row wv (chunk-granular) via global_load_lds x16B ----
  size_t rowoff = (size_t)(b*16 + wv)*NSEQ + i;
  const float* src = pre + rowoff*JCOL;
  float* Srow = S + wv*1280;
  for (int r = 0; r < rmaxC; r++)
    gld16(src + r*256 + lane*4, (void*)(Srow + r*256 + lane*4));
  __builtin_amdgcn_s_waitcnt(0);
  __syncthreads();

  // ---- phase 2: th_pre mix -> sortable keys (b128 LDS reads, 4 cols/lane) ----
  int h16 = __builtin_amdgcn_readfirstlane(wv) * 16;
  float TPr[16];
  #pragma unroll
  for (int g=0; g<16; g++) TPr[g] = th_pre[h16 + g];

  const unsigned KM = 0x00800000u;       // key_of(MASKV)
  unsigned kr[NCH][4];
  #pragma unroll
  for (int r=0;r<NCH;r++){ kr[r][0]=KM; kr[r][1]=KM; kr[r][2]=KM; kr[r][3]=KM; }
  #pragma unroll
  for (int r=0;r<NCH;r++) if (r < rmaxC){
    int j0 = r*256 + lane*4;
    f32x4 a = (f32x4){0.f,0.f,0.f,0.f};
    #pragma unroll
    for (int g=0; g<16; g++){
      f32x4 sv = *(const f32x4*)(S + g*1280 + j0);
      a += sv * TPr[g];
    }
    #pragma unroll
    for (int c=0;c<4;c++) if (j0 + c < vend) kr[r][c] = key_of(a[c]);
  }
  __syncthreads();   // all phase-2 S reads done; S reused for post stash below

  // ---- phase 3: exact top-64 threshold, 1 bit/iter; only active chunks counted,
  //      out-of-chunk masked slots contribute a wave-uniform scalar term ----
  int mslots = (NCH - rmaxC) * 256;      // masked slots outside active chunks (per wave)
  unsigned T = 0;
  for (int bit=31; bit>=0; --bit){
    unsigned cand = T | (1u << bit);
    int lc = 0;
    #pragma unroll
    for (int r=0;r<NCH;r++) if (r < rmaxC){
      #pragma unroll
      for (int c=0;c<4;c++) lc += (kr[r][c] >= cand) ? 1 : 0;
    }
    int tot = dpp_add_i(lc) + ((KM >= cand) ? mslots : 0);
    if (tot >= 64){
      T = cand;
      if (tot == 64) break;   // set {k >= cand} == top-64 set exactly
    }
  }
  // row max from keys (valid entries always exist and dominate KM)
  unsigned km = KM;
  #pragma unroll
  for (int r=0;r<NCH;r++) if (r < rmaxC){
    #pragma unroll
    for (int c=0;c<4;c++){ unsigned kk = kr[r][c]; km = kk > km ? kk : km; }
  }
  km = dpp_max_u(km);
  float mx = val_of(km);
  float s = 0.f;
  #pragma unroll
  for (int r=0;r<NCH;r++) if (r < rmaxC){
    #pragma unroll
    for (int c=0;c<4;c++){
      unsigned kk = kr[r][c];
      float ev = (kk >= T) ? __expf(val_of(kk) - mx) : 0.f;  // masked -> exp(-huge)=0
      s += ev;
      kr[r][c] = __float_as_uint(ev);     // stash exp for phase 4
    }
  }
  s = dpp_add_f(s);
  float inv = 1.f / s;

  // ---- phase 4: write post row wv + stash p into S (f32x4) ----
  float* drow = post + rowoff*JCOL;
  #pragma unroll
  for (int r=0;r<NCH;r++) if (r < rmaxC){
    int j0 = r*256 + lane*4;
    f32x4 p;
    #pragma unroll
    for (int c=0;c<4;c++) p[c] = __uint_as_float(kr[r][c]) * inv;
    *(f32x4*)(Srow + j0) = p;
    if (j0 + 3 < JCOL){
      *(f32x2*)(drow + j0)     = (f32x2){p[0], p[1]};
      *(f32x2*)(drow + j0 + 2) = (f32x2){p[2], p[3]};
    } else {
      #pragma unroll
      for (int c=0;c<4;c++) if (j0 + c < JCOL) drow[j0+c] = p[c];
    }
  }
  for (int j = rmaxC*256 + lane; j < JCOL; j += 64) drow[j] = 0.f;
  __syncthreads();

  // ---- phase 5: th_post mix, transposed: wave = (h-pair, chunk-half) ----
  int hp = __builtin_amdgcn_readfirstlane(wv >> 1);   // 0..7
  int cq = __builtin_amdgcn_readfirstlane(wv & 1);    // 0..1
  float tq0[16], tq1[16];
  #pragma unroll
  for (int g=0; g<16; g++){
    tq0[g] = th_post[(hp*2  )*16 + g];
    tq1[g] = th_post[(hp*2+1)*16 + g];
  }
  ushort_t* am0 = AM + ((size_t)(b*16 + hp*2  )*NSEQ + i)*JP;
  ushort_t* am1 = AM + ((size_t)(b*16 + hp*2+1)*NSEQ + i)*JP;
  for (int r = cq; r < rmaxC; r += 2){
    int j0 = r*256 + lane*4;
    f32x4 a0 = (f32x4){0.f,0.f,0.f,0.f};
    f32x4 a1 = (f32x4){0.f,0.f,0.f,0.f};
    #pragma unroll
    for (int g=0; g<16; g++){
      f32x4 sv = *(const f32x4*)(S + g*1280 + j0);
      a0 += sv * tq0[g];
      a1 += sv * tq1[g];
    }
    if (j0 + 3 < JP){
      short4v v0 = (short4v){(short)f2b(a0[0]),(short)f2b(a0[1]),(short)f2b(a0[2]),(short)f2b(a0[3])};
      short4v v1 = (short4v){(short)f2b(a1[0]),(short)f2b(a1[1]),(short)f2b(a1[2]),(short)f2b(a1[3])};
      *(short4v*)(am0 + j0) = v0;
      *(short4v*)(am1 + j0) = v1;
    } else {
      #pragma unroll
      for (int c=0;c<4;c++) if (j0 + c < JP){
        am0[j0+c] = f2b(a0[c]);
        am1[j0+c] = f2b(a1[c]);
      }
    }
  }
  // AM tail zeros only to the region k_pv actually reads: zend = (i&~63)+96
  {
    int zend = (i & ~63) + 96; if (zend > JP) zend = JP;
    ushort_t* amw = AM + ((size_t)(b*16 + wv)*NSEQ + i)*JP;
    for (int j = rmaxC*256 + lane; j < zend; j += 64) amw[j] = 0;
  }
}

// ---------------- PV: O1 = AM . Vt^T (causal kend) ----------------
__global__ __launch_bounds__(256) void k_pv(const ushort_t* __restrict__ AM,
        const ushort_t* __restrict__ Vt, ushort_t* __restrict__ O1){
  __shared__ __attribute__((aligned(16))) ushort_t As[64*32];
  __shared__ __attribute__((aligned(16))) ushort_t Bs[64*32];
  int tid = threadIdx.x;
  int m0 = blockIdx.x*64;
  int bh = blockIdx.y;
  const ushort_t* Ab = AM + (size_t)bh*NSEQ*JP + (size_t)m0*JP;
  const ushort_t* Bb = Vt + (size_t)bh*64*JP;
  int w=tid>>6, lane=tid&63, n15=lane&15, quad=lane>>4;
  int r=tid>>2, seg=tid&3;
  f32x4 acc[4];
  #pragma unroll
  for (int t=0;t<4;t++) acc[t] = (f32x4){0.f,0.f,0.f,0.f};
  int kend = m0 + 96; if (kend > JP) kend = JP;   // AM[i][j]=0 for j>i+2
  for (int k0=0;k0<kend;k0+=32){
    __syncthreads();
    gld16(Ab + (size_t)r*JP + k0 + seg*8, (void*)(As + tid*8));
    gld16(Bb + (size_t)r*JP + k0 + seg*8, (void*)(Bs + tid*8));
    __builtin_amdgcn_s_waitcnt(0);
    __syncthreads();
    short8 a = *(const short8*)(As + (w*16+n15)*32 + quad*8);
    #pragma unroll
    for (int t=0;t<4;t++){
      short8 b = *(const short8*)(Bs + (t*16+n15)*32 + quad*8);
      acc[t] = __builtin_amdgcn_mfma_f32_16x16x32_bf16(a, b, acc[t], 0,0,0);
    }
  }
  int b_ = bh>>4, h_ = bh&15;
  int rowbase = m0 + w*16 + quad*4;
  #pragma unroll
  for (int t=0;t<4;t++)
    #pragma unroll
    for (int rr=0;rr<4;rr++)
      O1[((size_t)b_*NSEQ + rowbase+rr)*1024 + h_*64 + t*16 + n15] = f2b(acc[t][rr]);
}

// ---------------- out = O1 . WoT^T (fp32 out, BM=128) ----------------
__global__ __launch_bounds__(256) void k_outproj(const ushort_t* __restrict__ o1,
        const ushort_t* __restrict__ wot, float* __restrict__ outp){
  __shared__ __attribute__((aligned(16))) ushort_t As[128*32];
  __shared__ __attribute__((aligned(16))) ushort_t Bs[64*32];
  int tid = threadIdx.x;
  int m0 = blockIdx.x*128;
  int n0 = blockIdx.y*64;
  int w = tid>>6, lane = tid&63, n15 = lane&15, quad = lane>>4;
  int r = tid>>2, seg = tid&3;
  f32x4 acc[2][4];
  #pragma unroll
  for (int m=0;m<2;m++)
    #pragma unroll
    for (int t=0;t<4;t++) acc[m][t] = (f32x4){0.f,0.f,0.f,0.f};
  for (int k0=0;k0<1024;k0+=32){
    __syncthreads();
    gld16(o1  + (size_t)(m0 + r)*1024 + k0 + seg*8,      (void*)(As + tid*8));
    gld16(o1  + (size_t)(m0 + 64 + r)*1024 + k0 + seg*8, (void*)(As + 2048 + tid*8));
    gld16(wot + (size_t)(n0 + r)*1024 + k0 + seg*8,      (void*)(Bs + tid*8));
    __builtin_amdgcn_s_waitcnt(0);
    __syncthreads();
    #pragma unroll
    for (int m=0;m<2;m++){
      short8 a = *(const short8*)(As + (w*32 + m*16 + n15)*32 + quad*8);
      #pragma unroll
      for (int t=0;t<4;t++){
        short8 b = *(const short8*)(Bs + (t*16 + n15)*32 + quad*8);
        acc[m][t] = __builtin_amdgcn_mfma_f32_16x16x32_bf16(a, b, acc[m][t], 0,0,0);
      }
    }
  }
  #pragma unroll
  for (int m=0;m<2;m++){
    int rowbase = m0 + w*32 + m*16 + quad*4;
    #pragma unroll
    for (int t=0;t<4;t++)
      #pragma unroll
      for (int rr=0;rr<4;rr++)
        outp[(size_t)(rowbase+rr)*1024 + n0 + t*16 + n15] = acc[m][t][rr];
  }
}

extern "C" void kernel_launch(void* const* d_in, const int* in_sizes, int n_in,
                              void* d_out, int out_size, void* d_ws, size_t ws_size,
                              hipStream_t stream){
  const float* x   = (const float*)d_in[0];
  const float* rpe = (const float*)d_in[1];
  const float* Wq  = (const float*)d_in[2];
  const float* Wk  = (const float*)d_in[3];
  const float* Wv  = (const float*)d_in[4];
  const float* Wo  = (const float*)d_in[5];
  const float* mk  = (const float*)d_in[6];
  const float* mv  = (const float*)d_in[7];
  const float* thp = (const float*)d_in[8];
  const float* thq = (const float*)d_in[9];
  char* ws = (char*)d_ws;
  ushort_t* AM = (ushort_t*)(ws + 0);              // 2*16*1024*1056 bf16 = 69.2 MB
  ushort_t* Qn = (ushort_t*)(ws + 69206016);       // 4.19 MB
  ushort_t* Kn = (ushort_t*)(ws + 73400320);       // 4.46 MB (rows padded to 1088)
  ushort_t* Vt = (ushort_t*)(ws + 77856768);       // 4.33 MB (cols padded to 1056)
  ushort_t* O1 = (ushort_t*)(ws + 82182144);       // 4.19 MB
  ushort_t* WT = (ushort_t*)(ws + 86376448);       // 4 x 2.10 MB transposed bf16 weights
  ushort_t* Xb = (ushort_t*)(ws + 94765056);       // 4.19 MB bf16 x
  float* out0 = (float*)d_out;
  float* pre  = out0 + 2097152;
  float* post = pre + 33619968;

  k_prep<<<dim3(16,16,6), 256, 0, stream>>>(Wq, Wk, Wv, Wo, WT,
                                            (const float4*)x, Xb, mk, mv, Kn, Vt);
  k_qkv<<<dim3(16,48), 256, 0, stream>>>(Xb, WT, rpe, Qn, Kn, Vt);
  k_dots<<<dim3(16,17,32), 256, 0, stream>>>(Qn, Kn, pre);
  k_mixsoft<<<2048, 1024, 0, stream>>>(pre, post, AM, thp, thq);
  k_pv<<<dim3(16,32), 256, 0, stream>>>(AM, Vt, O1);
  k_outproj<<<dim3(16,16), 256, 0, stream>>>(O1, WT + 3*1048576, out0);
}